// Round 1
// baseline (75.514 us; speedup 1.0000x reference)
//
#include <hip/hip_runtime.h>
#include <math.h>

#define PI_F 3.14159265358979323846f

// RX gate on the qubit with index-stride S (qubit q has stride 16>>q).
// Matrix [[c, -i s], [-i s, c]] applied to each (bit=0, bit=1) amplitude pair.
template<int S>
__device__ __forceinline__ void apply_rx(float* sr, float* si, float c, float s) {
#pragma unroll
    for (int i = 0; i < 32; ++i) {
        if (i & S) continue;
        const int j = i + S;
        const float r0 = sr[i], m0 = si[i], r1 = sr[j], m1 = si[j];
        // n0 = c*a0 - i*s*a1 ; n1 = -i*s*a0 + c*a1
        sr[i] = fmaf(c, r0,  s * m1);
        si[i] = fmaf(c, m0, -s * r1);
        sr[j] = fmaf(c, r1,  s * m0);
        si[j] = fmaf(c, m1, -s * r0);
    }
}

// CX^e with control stride Sc, target stride St. On control=1 subspace:
// [[A,B],[B,A]], A=(1+lam)/2, B=(1-lam)/2, lam=exp(i*pi*e).
template<int Sc, int St>
__device__ __forceinline__ void apply_cxpow(float* sr, float* si, float e) {
    float sl, cl;
    sincosf(PI_F * e, &sl, &cl);
    const float ar = 0.5f * (1.0f + cl), ai =  0.5f * sl;
    const float br = 0.5f * (1.0f - cl), bi = -0.5f * sl;
#pragma unroll
    for (int i = 0; i < 32; ++i) {
        if (!(i & Sc) || (i & St)) continue;   // control bit set, target bit clear
        const int j = i + St;
        const float r0 = sr[i], m0 = si[i], r1 = sr[j], m1 = si[j];
        sr[i] = ar * r0 - ai * m0 + br * r1 - bi * m1;
        si[i] = ar * m0 + ai * r0 + br * m1 + bi * r1;
        sr[j] = br * r0 - bi * m0 + ar * r1 - ai * m1;
        si[j] = br * m0 + bi * r0 + ar * m1 + ai * r1;
    }
}

// CZ^e on qubits (1,0): amplitudes with q0-bit (16) and q1-bit (8) both set
// get multiplied by lam = exp(i*pi*e).
__device__ __forceinline__ void apply_czpow(float* sr, float* si, float e) {
    float sl, cl;
    sincosf(PI_F * e, &sl, &cl);
#pragma unroll
    for (int i = 0; i < 32; ++i) {
        if ((i & 24) != 24) continue;
        const float r = sr[i], m = si[i];
        sr[i] = r * cl - m * sl;
        si[i] = r * sl + m * cl;
    }
}

__global__ __launch_bounds__(256)
void u1_circuit_kernel(const float* __restrict__ inp,   // (32,32,32,3)
                       const float* __restrict__ ker,   // (8,1,15) -> rows of 15
                       float* __restrict__ out,         // (32,31,31,8)
                       int total) {
    const int t = blockIdx.x * blockDim.x + threadIdx.x;
    if (t >= total) return;

    const int r   = t & 7;       // param row (fastest output axis -> coalesced store)
    const int pix = t >> 3;      // (b*31 + ix)*31 + iy
    const int iy  = pix % 31;
    const int tq  = pix / 31;
    const int ix  = tq % 31;
    const int b   = tq / 31;

    const float* xp = inp + ((size_t)(b * 32 + ix) * 32 + iy) * 3;
    const float* pp = ker + r * 15;

    // 5-qubit state in registers: 32 complex amplitudes.
    float sr[32], si[32];
#pragma unroll
    for (int i = 0; i < 32; ++i) { sr[i] = 0.0f; si[i] = 0.0f; }
    // |00000> then H on qubit 0:
    sr[0]  = 0.70710678118654752440f;
    sr[16] = 0.70710678118654752440f;

#pragma unroll
    for (int j = 0; j < 3; ++j) {
        // Four corner angles for channel j: (ix,iy),(ix,iy+1),(ix+1,iy),(ix+1,iy+1)
        const float a0 = xp[j];
        const float a1 = xp[3 + j];
        const float a2 = xp[96 + j];
        const float a3 = xp[99 + j];
        float c, s;
        sincosf(0.5f * PI_F * a0, &s, &c); apply_rx<8>(sr, si, c, s);  // qubit 1
        sincosf(0.5f * PI_F * a1, &s, &c); apply_rx<4>(sr, si, c, s);  // qubit 2
        sincosf(0.5f * PI_F * a2, &s, &c); apply_rx<2>(sr, si, c, s);  // qubit 3
        sincosf(0.5f * PI_F * a3, &s, &c); apply_rx<1>(sr, si, c, s);  // qubit 4

        const float* p = pp + 5 * j;
        apply_cxpow<8, 4>(sr, si, p[0]);   // (q1 -> q2)
        apply_cxpow<4, 2>(sr, si, p[1]);   // (q2 -> q3)
        apply_cxpow<2, 1>(sr, si, p[2]);   // (q3 -> q4)
        apply_cxpow<1, 8>(sr, si, p[3]);   // (q4 -> q1)
        apply_czpow(sr, si, p[4]);         // (q1, q0)
    }

    // <X_0> = 2 * sum_k Re(conj(amp[k]) * amp[k+16])
    float dot = 0.0f;
#pragma unroll
    for (int k = 0; k < 16; ++k)
        dot += sr[k] * sr[k + 16] + si[k] * si[k + 16];
    float e = 2.0f * dot;
    e = fminf(fmaxf(e, -1.0f + 1e-5f), 1.0f - 1e-5f);
    out[t] = acosf(e) * (1.0f / PI_F);
}

extern "C" void kernel_launch(void* const* d_in, const int* in_sizes, int n_in,
                              void* d_out, int out_size, void* d_ws, size_t ws_size,
                              hipStream_t stream) {
    const float* inp = (const float*)d_in[0];   // (32,32,32,3) fp32
    const float* ker = (const float*)d_in[1];   // (8,1,15)     fp32
    float* out = (float*)d_out;                 // (32,31,31,8) fp32
    const int total = out_size;                 // 246016
    const int block = 256;
    const int grid = (total + block - 1) / block;
    u1_circuit_kernel<<<grid, block, 0, stream>>>(inp, ker, out, total);
}

// Round 2
// 67.427 us; speedup vs baseline: 1.1199x; 1.1199x over previous
//
#include <hip/hip_runtime.h>
#include <math.h>

#define PI_F 3.14159265358979323846f

// All 16-amp states index qubits as: bit8=q1, bit4=q2, bit2=q3, bit1=q4.

// RX on stride-S qubit: [[c,-is],[-is,c]]
template<int S>
__device__ __forceinline__ void rx16(float* sr, float* si, float c, float s) {
#pragma unroll
    for (int i = 0; i < 16; ++i) {
        if (i & S) continue;
        const int j = i + S;
        const float r0 = sr[i], m0 = si[i], r1 = sr[j], m1 = si[j];
        sr[i] = fmaf(c, r0,  s * m1);
        si[i] = fmaf(c, m0, -s * r1);
        sr[j] = fmaf(c, r1,  s * m0);
        si[j] = fmaf(c, m1, -s * r0);
    }
}

// CX^e, control stride Sc, target stride St. B=(1-lam)/2; since A+B=1:
// new0 = a0 + B*(a1-a0), new1 = a1 - B*(a1-a0).
template<int Sc, int St>
__device__ __forceinline__ void cx16(float* sr, float* si, float br, float bi) {
#pragma unroll
    for (int i = 0; i < 16; ++i) {
        if (!(i & Sc) || (i & St)) continue;
        const int j = i + St;
        const float dr = sr[j] - sr[i], di = si[j] - si[i];
        const float ur = br * dr - bi * di;
        const float ui = fmaf(br, di, bi * dr);
        sr[i] += ur; si[i] += ui;
        sr[j] -= ur; si[j] -= ui;
    }
}

// CZ phase lam=(cl,sl) on q1=1 half (bit8) — applied to psi1 only.
__device__ __forceinline__ void cz16(float* sr, float* si, float cl, float sl) {
#pragma unroll
    for (int m = 0; m < 16; ++m) {
        if (!(m & 8)) continue;
        const float r = sr[m], q = si[m];
        sr[m] = r * cl - q * sl;
        si[m] = fmaf(r, sl, q * cl);
    }
}

// B = (1 - e^{i*pi*e})/2 via hw trig (revolutions: sin(pi*e)=v_sin(e/2)).
__device__ __forceinline__ void bcoef(float e, float& br, float& bi) {
    const float rev = e * 0.5f;
    const float sl = __builtin_amdgcn_sinf(rev);
    const float cl = __builtin_amdgcn_cosf(rev);
    br = 0.5f * (1.0f - cl);
    bi = -0.5f * sl;
}

__global__ __launch_bounds__(256)
void u1_circuit_kernel(const float* __restrict__ inp,   // (32,32,32,3)
                       const float* __restrict__ ker,   // (8,1,15)
                       float* __restrict__ out,         // (32,31,31,8)
                       int total) {
    const int t = blockIdx.x * blockDim.x + threadIdx.x;
    if (t >= total) return;

    const int r   = t & 7;
    const int pix = t >> 3;
    const int iy  = pix % 31;
    const int tq  = pix / 31;
    const int ix  = tq % 31;
    const int b   = tq / 31;

    const float* xp = inp + ((size_t)(b * 32 + ix) * 32 + iy) * 3;
    const float* pp = ker + r * 15;

    // ---------- layer 0: RX product state on q1..q4 (q0 handled analytically)
    // RX(pi*a)|0> = cos(pi*a/2)|0> - i sin(pi*a/2)|1>; rev = a/4.
    float c1, s1, c2, s2, c3, s3, c4, s4;
    {
        const float a0 = xp[0], a1 = xp[3], a2 = xp[96], a3 = xp[99];
        s1 = __builtin_amdgcn_sinf(a0 * 0.25f); c1 = __builtin_amdgcn_cosf(a0 * 0.25f);
        s2 = __builtin_amdgcn_sinf(a1 * 0.25f); c2 = __builtin_amdgcn_cosf(a1 * 0.25f);
        s3 = __builtin_amdgcn_sinf(a2 * 0.25f); c3 = __builtin_amdgcn_cosf(a2 * 0.25f);
        s4 = __builtin_amdgcn_sinf(a3 * 0.25f); c4 = __builtin_amdgcn_cosf(a3 * 0.25f);
    }
    // magnitude product tree: mg[m] = prod over bits (s_k if set else c_k)
    float t2[4], t3[8], mg[16];
    t2[0] = c1 * c2; t2[1] = c1 * s2; t2[2] = s1 * c2; t2[3] = s1 * s2;
#pragma unroll
    for (int x = 0; x < 8; ++x)  t3[x] = t2[x >> 1] * ((x & 1) ? s3 : c3);
#pragma unroll
    for (int x = 0; x < 16; ++x) mg[x] = t3[x >> 1] * ((x & 1) ? s4 : c4);

    // amp[m] = (-i)^popcount(m) * mg[m]  (zeros constant-fold into first CX)
    float p0r[16], p0i[16];
#pragma unroll
    for (int m = 0; m < 16; ++m) {
        const int pc = __builtin_popcount(m) & 3;
        p0r[m] = (pc == 0) ? mg[m] : ((pc == 2) ? -mg[m] : 0.0f);
        p0i[m] = (pc == 1) ? -mg[m] : ((pc == 3) ? mg[m] : 0.0f);
    }

    float br, bi;
    bcoef(pp[0], br, bi); cx16<8, 4>(p0r, p0i, br, bi);
    bcoef(pp[1], br, bi); cx16<4, 2>(p0r, p0i, br, bi);
    bcoef(pp[2], br, bi); cx16<2, 1>(p0r, p0i, br, bi);
    bcoef(pp[3], br, bi); cx16<1, 8>(p0r, p0i, br, bi);

    // first CZ: psi1 = psi0 with phase lam on q1=1 half; psi0 unchanged.
    float p1r[16], p1i[16];
    {
        const float rev = pp[4] * 0.5f;
        const float sl = __builtin_amdgcn_sinf(rev);
        const float cl = __builtin_amdgcn_cosf(rev);
#pragma unroll
        for (int m = 0; m < 16; ++m) {
            if (m & 8) {
                p1r[m] = p0r[m] * cl - p0i[m] * sl;
                p1i[m] = fmaf(p0r[m], sl, p0i[m] * cl);
            } else {
                p1r[m] = p0r[m];
                p1i[m] = p0i[m];
            }
        }
    }

    // ---------- layers 1..2: same RX/CX on both halves; CZ phases psi1 only
#pragma unroll
    for (int j = 1; j < 3; ++j) {
        const float a0 = xp[j], a1 = xp[3 + j], a2 = xp[96 + j], a3 = xp[99 + j];
        float c, s;
        s = __builtin_amdgcn_sinf(a0 * 0.25f); c = __builtin_amdgcn_cosf(a0 * 0.25f);
        rx16<8>(p0r, p0i, c, s); rx16<8>(p1r, p1i, c, s);
        s = __builtin_amdgcn_sinf(a1 * 0.25f); c = __builtin_amdgcn_cosf(a1 * 0.25f);
        rx16<4>(p0r, p0i, c, s); rx16<4>(p1r, p1i, c, s);
        s = __builtin_amdgcn_sinf(a2 * 0.25f); c = __builtin_amdgcn_cosf(a2 * 0.25f);
        rx16<2>(p0r, p0i, c, s); rx16<2>(p1r, p1i, c, s);
        s = __builtin_amdgcn_sinf(a3 * 0.25f); c = __builtin_amdgcn_cosf(a3 * 0.25f);
        rx16<1>(p0r, p0i, c, s); rx16<1>(p1r, p1i, c, s);

        const float* p = pp + 5 * j;
        bcoef(p[0], br, bi); cx16<8, 4>(p0r, p0i, br, bi); cx16<8, 4>(p1r, p1i, br, bi);
        bcoef(p[1], br, bi); cx16<4, 2>(p0r, p0i, br, bi); cx16<4, 2>(p1r, p1i, br, bi);
        bcoef(p[2], br, bi); cx16<2, 1>(p0r, p0i, br, bi); cx16<2, 1>(p1r, p1i, br, bi);
        bcoef(p[3], br, bi); cx16<1, 8>(p0r, p0i, br, bi); cx16<1, 8>(p1r, p1i, br, bi);

        const float rev = p[4] * 0.5f;
        cz16(p1r, p1i, __builtin_amdgcn_cosf(rev), __builtin_amdgcn_sinf(rev));
    }

    // <X0> = sum Re(conj(psi0)*psi1)  (the two 1/sqrt2 factors cancel the 2x)
    float dot = 0.0f;
#pragma unroll
    for (int m = 0; m < 16; ++m)
        dot = fmaf(p0r[m], p1r[m], fmaf(p0i[m], p1i[m], dot));

    dot = fminf(fmaxf(dot, -1.0f + 1e-5f), 1.0f - 1e-5f);
    out[t] = acosf(dot) * (1.0f / PI_F);
}

extern "C" void kernel_launch(void* const* d_in, const int* in_sizes, int n_in,
                              void* d_out, int out_size, void* d_ws, size_t ws_size,
                              hipStream_t stream) {
    const float* inp = (const float*)d_in[0];   // (32,32,32,3) fp32
    const float* ker = (const float*)d_in[1];   // (8,1,15)     fp32
    float* out = (float*)d_out;                 // (32,31,31,8) fp32
    const int total = out_size;                 // 246016
    const int block = 256;
    const int grid = (total + block - 1) / block;
    u1_circuit_kernel<<<grid, block, 0, stream>>>(inp, ker, out, total);
}